// Round 16
// baseline (1518.062 us; speedup 1.0000x reference)
//
#include <hip/hip_runtime.h>
#include <hip/hip_bf16.h>
#include <cstddef>

namespace {

constexpr int NB   = 8;     // batch
constexpr int LSEQ = 1025;  // tokens incl. CLS
constexpr int TSEQ = 1024;
constexpr int DM   = 192;   // d_model
constexpr int DI   = 384;   // d_inner
constexpr int DXZ  = 768;   // 2*d_inner
constexpr int DBLW = 140;   // dt_rank + 2*d_state
constexpr int DTR  = 12;    // dt_rank
constexpr int NST  = 64;    // d_state
constexpr int MROWS = NB * LSEQ;  // 8200
constexpr int NCH  = 32;    // scan chunks
constexpr int CS   = 32;    // chunk size (last chunk = 33)
constexpr int NCH1 = NCH - 1;
constexpr int NDG  = DI / 64;  // 6 channel groups
constexpr int HST  = 32;    // states per wave (half split)
constexpr int XPAD = 144;   // padded rows for xp weight
constexpr float LOG2E = 1.4426950408889634f;

using bf16x8 = __attribute__((ext_vector_type(8))) short;
using f32x4  = __attribute__((ext_vector_type(4))) float;

__device__ __forceinline__ float waveReduceSum(float v) {
#pragma unroll
  for (int o = 32; o; o >>= 1) v += __shfl_xor(v, o, 64);
  return v;
}

__device__ __forceinline__ unsigned short f2bf(float v) {
  __hip_bfloat16 b = __float2bfloat16(v);
  return *reinterpret_cast<unsigned short*>(&b);
}
__device__ __forceinline__ float bf2f(unsigned short u) {
  return __uint_as_float(((unsigned)u) << 16);
}
__device__ __forceinline__ float lo16(unsigned v) { return __uint_as_float(v << 16); }
__device__ __forceinline__ float hi16(unsigned v) { return __uint_as_float(v & 0xffff0000u); }
__device__ __forceinline__ unsigned addpair_bf(unsigned a, unsigned b) {
  float alo = lo16(a), ahi = hi16(a);
  float blo = lo16(b), bhi = hi16(b);
  return ((unsigned)f2bf(alo + blo)) | (((unsigned)f2bf(ahi + bhi)) << 16);
}

// ---------------- embed ----------------
__global__ void embed_kernel(const int* __restrict__ ids, const float* __restrict__ emb,
                             const float* __restrict__ cls, float* __restrict__ x) {
  int idx = blockIdx.x * blockDim.x + threadIdx.x;
  if (idx >= NB * LSEQ * DM) return;
  int d = idx % DM;
  int bt = idx / DM;
  int t = bt % LSEQ, b = bt / LSEQ;
  float v;
  if (t < TSEQ) v = emb[(size_t)ids[b * TSEQ + t] * DM + d];
  else          v = cls[d];
  x[idx] = v;
}

// ---------------- weight conversion ----------------
__global__ void cvt_bf16_kernel(const float* __restrict__ src, unsigned short* __restrict__ dst,
                                int n) {
  int idx = blockIdx.x * blockDim.x + threadIdx.x;
  if (idx < n) dst[idx] = f2bf(src[idx]);
}

__global__ void pad_xp_kernel(const float* __restrict__ src, unsigned short* __restrict__ dst) {
  int idx = blockIdx.x * blockDim.x + threadIdx.x;
  if (idx >= 8 * XPAD * DI) return;
  int k = idx % DI;
  int n = (idx / DI) % XPAD;
  int l = idx / (DI * XPAD);
  float v = (n < DBLW) ? src[((size_t)l * DBLW + n) * DI + k] : 0.f;
  dst[idx] = f2bf(v);
}

// ---------------- batched transpose (for dtw only) ----------------
__global__ void transpose_batched(const float* __restrict__ in, float* __restrict__ out,
                                  int rows, int cols) {
  __shared__ float tile[32][33];
  int l = blockIdx.z;
  int r0 = blockIdx.y * 32, c0 = blockIdx.x * 32;
  const float* src = in + (size_t)l * rows * cols;
  float* dst = out + (size_t)l * rows * cols;
  int tx = threadIdx.x, ty = threadIdx.y;
#pragma unroll
  for (int i = 0; i < 32; i += 8) {
    int r = r0 + ty + i, c = c0 + tx;
    if (r < rows && c < cols) tile[ty + i][tx] = src[(size_t)r * cols + c];
  }
  __syncthreads();
#pragma unroll
  for (int i = 0; i < 32; i += 8) {
    int c = c0 + ty + i, r = r0 + tx;
    if (c < cols && r < rows) dst[(size_t)c * rows + r] = tile[tx][ty + i];
  }
}

// ---------------- rmsnorm -> bf16 ----------------
__global__ __launch_bounds__(192)
void rmsnorm_kernel(const float* __restrict__ x, const float* __restrict__ w,
                    unsigned short* __restrict__ h) {
  int row = blockIdx.x;
  int d = threadIdx.x;
  float v = x[(size_t)row * DM + d];
  float ss = waveReduceSum(v * v);
  __shared__ float red[3];
  if ((d & 63) == 0) red[d >> 6] = ss;
  __syncthreads();
  float ms = (red[0] + red[1] + red[2]) * (1.f / DM);
  h[(size_t)row * DM + d] = f2bf(v * rsqrtf(ms + 1e-6f) * w[d]);
}

// ---------------- bf16 MFMA GEMM: C[M,*] op= A[M,K] @ W[N,K]^T ----------------
// EPI: 0 = store fp32 C, 1 = += fp32 C, 2 = store bf16 Cb.
// ASRC: 0 = A bf16, 1 = A = bf16sum(Ab0, Ab1).
template <int EPI, int ASRC>
__global__ __launch_bounds__(256)
void gemm_mfma(const unsigned short* __restrict__ A, const unsigned short* __restrict__ Ab0,
               const unsigned short* __restrict__ Ab1, const unsigned short* __restrict__ W,
               float* __restrict__ C, unsigned short* __restrict__ Cb,
               int M, int Nw, int Nstore, int K, int ldc) {
  __shared__ unsigned short Alds[128][40];
  __shared__ unsigned short Wlds[64][40];
  const int tid = threadIdx.x;
  const int w = tid >> 6, lane = tid & 63;
  const int r16 = lane & 15, g = lane >> 4;
  const int row0 = blockIdx.y * 128, col0 = blockIdx.x * 64;

  f32x4 acc[2][4];
#pragma unroll
  for (int mi = 0; mi < 2; ++mi)
#pragma unroll
    for (int ni = 0; ni < 4; ++ni) acc[mi][ni] = (f32x4){0.f, 0.f, 0.f, 0.f};

  for (int k0 = 0; k0 < K; k0 += 32) {
#pragma unroll
    for (int cc = 0; cc < 2; ++cc) {
      int c = tid + cc * 256;
      int r = c >> 2, q = c & 3;
      uint4 v = make_uint4(0, 0, 0, 0);
      int grow = row0 + r;
      if (grow < M) {
        if (ASRC == 0) {
          v = *(const uint4*)(A + (size_t)grow * K + k0 + q * 8);
        } else {
          uint4 a = *(const uint4*)(Ab0 + (size_t)grow * K + k0 + q * 8);
          uint4 b = *(const uint4*)(Ab1 + (size_t)grow * K + k0 + q * 8);
          v.x = addpair_bf(a.x, b.x);
          v.y = addpair_bf(a.y, b.y);
          v.z = addpair_bf(a.z, b.z);
          v.w = addpair_bf(a.w, b.w);
        }
      }
      *(uint4*)&Alds[r][q * 8] = v;
    }
    {
      int r = tid >> 2, q = tid & 3;
      uint4 v = make_uint4(0, 0, 0, 0);
      int gn = col0 + r;
      if (gn < Nw) v = *(const uint4*)(W + (size_t)gn * K + k0 + q * 8);
      *(uint4*)&Wlds[r][q * 8] = v;
    }
    __syncthreads();
    bf16x8 a_f[2], b_f[4];
#pragma unroll
    for (int mi = 0; mi < 2; ++mi)
      a_f[mi] = *(const bf16x8*)&Alds[w * 32 + mi * 16 + r16][g * 8];
#pragma unroll
    for (int ni = 0; ni < 4; ++ni)
      b_f[ni] = *(const bf16x8*)&Wlds[ni * 16 + r16][g * 8];
#pragma unroll
    for (int mi = 0; mi < 2; ++mi)
#pragma unroll
      for (int ni = 0; ni < 4; ++ni)
        acc[mi][ni] = __builtin_amdgcn_mfma_f32_16x16x32_bf16(a_f[mi], b_f[ni],
                                                              acc[mi][ni], 0, 0, 0);
    __syncthreads();
  }
#pragma unroll
  for (int mi = 0; mi < 2; ++mi) {
#pragma unroll
    for (int reg = 0; reg < 4; ++reg) {
      int row = row0 + w * 32 + mi * 16 + g * 4 + reg;
      if (row >= M) continue;
#pragma unroll
      for (int ni = 0; ni < 4; ++ni) {
        int col = col0 + ni * 16 + r16;
        if (col >= Nstore) continue;
        size_t idx = (size_t)row * ldc + col;
        if (EPI == 1)      C[idx] += acc[mi][ni][reg];
        else if (EPI == 0) C[idx] = acc[mi][ni][reg];
        else               Cb[idx] = f2bf(acc[mi][ni][reg]);
      }
    }
  }
}

// ------- depthwise causal conv3 (bf16 in) + bias + silu -> bf16 (x half only) -------
__global__ void conv_kernel(const unsigned short* __restrict__ xz16, const float* __restrict__ cw,
                            const float* __restrict__ cb,
                            unsigned short* __restrict__ xi16) {
  int idx = blockIdx.x * blockDim.x + threadIdx.x;
  if (idx >= NB * LSEQ * DI) return;
  int c = idx % DI;
  int bt = idx / DI;
  int t = bt % LSEQ, b = bt / LSEQ;
  const unsigned short* src = xz16 + (size_t)b * LSEQ * DXZ + c;
  float s = cb[c];
  float w0 = cw[c * 3 + 0], w1 = cw[c * 3 + 1], w2 = cw[c * 3 + 2];
  if (t >= 2) s = fmaf(w0, bf2f(src[(size_t)(t - 2) * DXZ]), s);
  if (t >= 1) s = fmaf(w1, bf2f(src[(size_t)(t - 1) * DXZ]), s);
  s = fmaf(w2, bf2f(src[(size_t)t * DXZ]), s);
  float sig = 1.f / (1.f + __expf(-s));
  xi16[idx] = f2bf(s * sig);
}

// ---------------- dt = softplus(dt_r @ dtwT + dtb), 4 rows per block ----------------
__global__ __launch_bounds__(384)
void dt_kernel(const float* __restrict__ dbl, const float* __restrict__ dtwT,
               const float* __restrict__ dtb, float* __restrict__ dtout) {
  int row0 = blockIdx.x * 4;
  int d = threadIdx.x;
  __shared__ float rr[4][DTR];
  if (d < 4 * DTR) rr[d / DTR][d % DTR] = dbl[(size_t)(row0 + d / DTR) * DBLW + (d % DTR)];
  float w[DTR];
#pragma unroll
  for (int r = 0; r < DTR; ++r) w[r] = dtwT[r * DI + d];
  float bias = dtb[d];
  __syncthreads();
#pragma unroll
  for (int q = 0; q < 4; ++q) {
    float s = bias;
#pragma unroll
    for (int r = 0; r < DTR; ++r) s = fmaf(rr[q][r], w[r], s);
    float sp = fmaxf(s, 0.f) + log1pf(__expf(-fabsf(s)));
    dtout[(size_t)(row0 + q) * DI + d] = sp;
  }
}

// ======== chunked selective scan, CS=32/NCH=32, half-split ========
// block = 384 threads = 6 waves = 3 dgroups x 2 state-halves; block -> (b, chunk, dhalf).
// Grid x2 vs 768-thr version -> up to 3 blocks/CU (18 waves) at VGPR<=102.
// FAST PATH (A_log structure a_n = -(n+1), __all-guarded): dA[n] = r^(n+1).
// H (bf16): H[((bg*NCH + c)*NST + n)*64 + lane]; pass1 -> H[c+1], pass2 in place.

__global__ __launch_bounds__(384, 5)
void scan_pass1(const float* __restrict__ dtp_, const unsigned short* __restrict__ xi16,
                const float* __restrict__ dbl, const float* __restrict__ Alog,
                float* __restrict__ cumdt, unsigned short* __restrict__ H) {
  __shared__ float Bt[CS][64];
  const int tid = threadIdx.x;
  const int w = tid >> 6, lane = tid & 63;
  const int dgrp_l = w >> 1, half = w & 1;
  const int b = blockIdx.x / (NCH1 * 2);
  const int rem = blockIdx.x % (NCH1 * 2);
  const int c = rem >> 1, dh = rem & 1;
  const int dgrp = dh * 3 + dgrp_l;
  const int bg = b * NDG + dgrp;
  const int d = dgrp * 64 + lane;
  const int n0 = half * HST;
  const int t0 = c * CS;

  {  // stage B tile once, all 6 waves
    const float* srcB = dbl + ((size_t)b * LSEQ + t0) * DBLW + DTR + lane;
    for (int r = w; r < CS; r += 6) Bt[r][lane] = srcB[(size_t)r * DBLW];
  }

  const float* Ap = Alog + (size_t)d * NST;
  float a0 = __expf(Ap[0]);
  bool okl = true;
#pragma unroll
  for (int j = 0; j < HST; ++j) {
    float aj = __expf(Ap[n0 + j]);
    okl = okl && (fabsf(aj - (float)(n0 + j + 1) * a0) <= 1e-3f * (float)(n0 + j + 1) * fabsf(a0));
  }
  const bool fast = __all(okl);
  const float al2u = -a0 * LOG2E;

  float h[HST];
#pragma unroll
  for (int j = 0; j < HST; ++j) h[j] = 0.f;

  __syncthreads();

  const float* dtp = dtp_ + ((size_t)b * LSEQ + t0) * DI + d;
  const unsigned short* up = xi16 + ((size_t)b * LSEQ + t0) * DI + d;
  float cum = 0.f;
  float dtv = *dtp, uv = bf2f(*up);

  if (fast) {
    for (int t = 0; t < CS; ++t) {
      float n_dt = 0.f, n_u = 0.f;
      if (t + 1 < CS) {
        dtp += DI; up += DI;
        n_dt = *dtp; n_u = bf2f(*up);
      }
      float dtu = dtv * uv;
      float m = dtv * al2u;
      float r1 = exp2f(m);
      float p = (n0 == 0) ? r1 : exp2f(m * (float)(n0 + 1));
      float r2 = r1 * r1, r4 = r2 * r2;
      float s0 = p, s1 = p * r1, s2 = p * r2, s3 = s2 * r1;
#pragma unroll
      for (int k = 0; k < 8; ++k) {
        float4 B4 = *(const float4*)&Bt[t][n0 + 4 * k];
        h[4 * k + 0] = fmaf(s0, h[4 * k + 0], dtu * B4.x);
        h[4 * k + 1] = fmaf(s1, h[4 * k + 1], dtu * B4.y);
        h[4 * k + 2] = fmaf(s2, h[4 * k + 2], dtu * B4.z);
        h[4 * k + 3] = fmaf(s3, h[4 * k + 3], dtu * B4.w);
        if (k < 7) { s0 *= r4; s1 *= r4; s2 *= r4; s3 *= r4; }
      }
      cum += dtv;
      dtv = n_dt; uv = n_u;
    }
  } else {
    for (int t = 0; t < CS; ++t) {
      float n_dt = 0.f, n_u = 0.f;
      if (t + 1 < CS) {
        dtp += DI; up += DI;
        n_dt = *dtp; n_u = bf2f(*up);
      }
      float dtu = dtv * uv;
      for (int j = 0; j < HST; ++j) {
        float aj = -__expf(Ap[n0 + j]) * LOG2E;
        h[j] = fmaf(exp2f(dtv * aj), h[j], dtu * Bt[t][n0 + j]);
      }
      cum += dtv;
      dtv = n_dt; uv = n_u;
    }
  }

  if (half == 0)
    cumdt[(size_t)bg * NCH1 * 64 + (size_t)c * 64 + lane] = cum;
  unsigned short* hp = H + ((size_t)bg * NCH + (c + 1)) * NST * 64 + (size_t)n0 * 64 + lane;
#pragma unroll
  for (int j = 0; j < HST; ++j) hp[j * 64] = f2bf(h[j]);
}

// pass2: in-place combine (bf16 H). wave = (bg, 4 states)
__global__ __launch_bounds__(256)
void scan_pass2(const float* __restrict__ cumdt, const float* __restrict__ Alog,
                unsigned short* __restrict__ H) {
  int gw = blockIdx.x * 4 + (threadIdx.x >> 6);   // wave id over NB*NDG*16
  int lane = threadIdx.x & 63;
  int bg = gw >> 4;
  int nq = (gw & 15) * 4;
  int dgrp = bg % NDG;
  int d = dgrp * 64 + lane;

  float al2[4];
#pragma unroll
  for (int j = 0; j < 4; ++j) al2[j] = -__expf(Alog[(size_t)d * NST + nq + j]) * LOG2E;

  float h[4] = {0.f, 0.f, 0.f, 0.f};

  unsigned short* H0 = H + ((size_t)bg * NCH) * NST * 64 + (size_t)nq * 64 + lane;
#pragma unroll
  for (int j = 0; j < 4; ++j) H0[j * 64] = 0;

  for (int c = 1; c < NCH; ++c) {
    float cum = cumdt[(size_t)bg * NCH1 * 64 + (size_t)(c - 1) * 64 + lane];
    unsigned short* Hc = H + ((size_t)bg * NCH + c) * NST * 64 + (size_t)nq * 64 + lane;
#pragma unroll
    for (int j = 0; j < 4; ++j) {
      float he = bf2f(Hc[j * 64]);
      h[j] = fmaf(exp2f(al2[j] * cum), h[j], he);
      Hc[j * 64] = f2bf(h[j]);
    }
  }
}

// pass3: scan from H[c]; gate z streamed from xz16 (silu in-loop);
// half0 -> yb0 (incl. D-skip), half1 -> yb1; bf16 out.
__global__ __launch_bounds__(384, 5)
void scan_pass3(const float* __restrict__ dtp_, const unsigned short* __restrict__ xi16,
                const unsigned short* __restrict__ xz16, const float* __restrict__ dbl,
                const float* __restrict__ Alog, const float* __restrict__ Dpar,
                const unsigned short* __restrict__ H, unsigned short* __restrict__ yb0,
                unsigned short* __restrict__ yb1) {
  __shared__ float Bt[CS + 1][64];
  __shared__ float Ct[CS + 1][64];
  const int tid = threadIdx.x;
  const int w = tid >> 6, lane = tid & 63;
  const int dgrp_l = w >> 1, half = w & 1;
  const int b = blockIdx.x / (NCH * 2);
  const int rem = blockIdx.x % (NCH * 2);
  const int c = rem >> 1, dh = rem & 1;
  const int dgrp = dh * 3 + dgrp_l;
  const int bg = b * NDG + dgrp;
  const int d = dgrp * 64 + lane;
  const int n0 = half * HST;
  const int t0 = c * CS;
  const int nsteps = (c == NCH - 1) ? (LSEQ - t0) : CS;   // 32 or 33

  {  // stage B (waves 0-2) and C (waves 3-5) once per block
    if (w < 3) {
      const float* srcB = dbl + ((size_t)b * LSEQ + t0) * DBLW + DTR + lane;
      for (int r = w; r < nsteps; r += 3) Bt[r][lane] = srcB[(size_t)r * DBLW];
    } else {
      const float* srcC = dbl + ((size_t)b * LSEQ + t0) * DBLW + DTR + NST + lane;
      for (int r = w - 3; r < nsteps; r += 3) Ct[r][lane] = srcC[(size_t)r * DBLW];
    }
  }

  const float* Ap = Alog + (size_t)d * NST;
  float a0 = __expf(Ap[0]);
  bool okl = true;
#pragma unroll
  for (int j = 0; j < HST; ++j) {
    float aj = __expf(Ap[n0 + j]);
    okl = okl && (fabsf(aj - (float)(n0 + j + 1) * a0) <= 1e-3f * (float)(n0 + j + 1) * fabsf(a0));
  }
  const bool fast = __all(okl);
  const float al2u = -a0 * LOG2E;

  float Dp = Dpar[d];
  float h[HST];
  {
    const unsigned short* hi = H + ((size_t)bg * NCH + c) * NST * 64 + (size_t)n0 * 64 + lane;
#pragma unroll
    for (int j = 0; j < HST; ++j) h[j] = bf2f(hi[j * 64]);
  }

  __syncthreads();

  const float* dtp = dtp_ + ((size_t)b * LSEQ + t0) * DI + d;
  const unsigned short* up = xi16 + ((size_t)b * LSEQ + t0) * DI + d;
  const unsigned short* zp = xz16 + ((size_t)b * LSEQ + t0) * DXZ + DI + d;
  unsigned short* yp = (half == 0 ? yb0 : yb1) + ((size_t)b * LSEQ + t0) * DI + d;

  float dtv = *dtp, uv = bf2f(*up), zv = bf2f(*zp);

  if (fast) {
    for (int t = 0; t < nsteps; ++t) {
      float n_dt = 0.f, n_u = 0.f, n_z = 0.f;
      if (t + 1 < nsteps) {
        dtp += DI; up += DI; zp += DXZ;
        n_dt = *dtp; n_u = bf2f(*up); n_z = bf2f(*zp);
      }
      float dtu = dtv * uv;
      float m = dtv * al2u;
      float r1 = exp2f(m);
      float p = (n0 == 0) ? r1 : exp2f(m * (float)(n0 + 1));
      float r2 = r1 * r1, r4 = r2 * r2;
      float s0 = p, s1 = p * r1, s2 = p * r2, s3 = s2 * r1;
      float y0 = 0.f, y1 = 0.f, y2 = 0.f, y3 = 0.f;
#pragma unroll
      for (int k = 0; k < 8; ++k) {
        float4 B4 = *(const float4*)&Bt[t][n0 + 4 * k];
        float4 C4 = *(const float4*)&Ct[t][n0 + 4 * k];
        h[4 * k + 0] = fmaf(s0, h[4 * k + 0], dtu * B4.x);
        y0 = fmaf(h[4 * k + 0], C4.x, y0);
        h[4 * k + 1] = fmaf(s1, h[4 * k + 1], dtu * B4.y);
        y1 = fmaf(h[4 * k + 1], C4.y, y1);
        h[4 * k + 2] = fmaf(s2, h[4 * k + 2], dtu * B4.z);
        y2 = fmaf(h[4 * k + 2], C4.z, y2);
        h[4 * k + 3] = fmaf(s3, h[4 * k + 3], dtu * B4.w);
        y3 = fmaf(h[4 * k + 3], C4.w, y3);
        if (k < 7) { s0 *= r4; s1 *= r4; s2 *= r4; s3 *= r4; }
      }
      float y = (y0 + y1) + (y2 + y3);
      float gv = zv / (1.f + __expf(-zv));
      float outv = (half == 0) ? fmaf(uv, Dp, y) * gv : y * gv;
      *yp = f2bf(outv);
      yp += DI;
      dtv = n_dt; uv = n_u; zv = n_z;
    }
  } else {
    for (int t = 0; t < nsteps; ++t) {
      float n_dt = 0.f, n_u = 0.f, n_z = 0.f;
      if (t + 1 < nsteps) {
        dtp += DI; up += DI; zp += DXZ;
        n_dt = *dtp; n_u = bf2f(*up); n_z = bf2f(*zp);
      }
      float dtu = dtv * uv;
      float y = 0.f;
      for (int j = 0; j < HST; ++j) {
        float aj = -__expf(Ap[n0 + j]) * LOG2E;
        h[j] = fmaf(exp2f(dtv * aj), h[j], dtu * Bt[t][n0 + j]);
        y = fmaf(h[j], Ct[t][n0 + j], y);
      }
      float gv = zv / (1.f + __expf(-zv));
      float outv = (half == 0) ? fmaf(uv, Dp, y) * gv : y * gv;
      *yp = f2bf(outv);
      yp += DI;
      dtv = n_dt; uv = n_u; zv = n_z;
    }
  }
}

// ---------------- final norm + masked mean pool + head ------------
__global__ __launch_bounds__(192)
void pool1_kernel(const float* __restrict__ x, const int* __restrict__ mask,
                  const float* __restrict__ fw, float* __restrict__ partial) {
  int b = blockIdx.x >> 6;
  int chunk = blockIdx.x & 63;
  int d = threadIdx.x;
  __shared__ float red[3];
  float w = fw[d];
  float acc = 0.f;
  for (int tt = 0; tt < 16; ++tt) {
    int t = chunk * 16 + tt;
    float v = x[((size_t)b * LSEQ + t) * DM + d];
    float ss = waveReduceSum(v * v);
    if ((d & 63) == 0) red[d >> 6] = ss;
    __syncthreads();
    float ms = (red[0] + red[1] + red[2]) * (1.f / DM);
    float m = (float)mask[b * TSEQ + t];
    acc = fmaf(v * rsqrtf(ms + 1e-6f) * w, m, acc);
    __syncthreads();
  }
  partial[((size_t)b * 64 + chunk) * DM + d] = acc;
}

__global__ __launch_bounds__(192)
void pool2_kernel(const float* __restrict__ partial, const int* __restrict__ mask,
                  const float* __restrict__ hw, const float* __restrict__ hb,
                  float* __restrict__ out) {
  int b = blockIdx.x;
  int d = threadIdx.x;
  float s = 0.f;
  for (int c = 0; c < 64; ++c) s += partial[((size_t)b * 64 + c) * DM + d];
  float den = 0.f;
  for (int t = d; t < TSEQ; t += DM) den += (float)mask[b * TSEQ + t];
  den = waveReduceSum(den);
  __shared__ float dred[3];
  __shared__ float pooled[DM];
  if ((d & 63) == 0) dred[d >> 6] = den;
  __syncthreads();
  float denom = fmaxf(dred[0] + dred[1] + dred[2], 1.f);
  pooled[d] = s / denom;
  __syncthreads();
  if (d < 2) {
    float acc = hb[d];
    for (int k = 0; k < DM; ++k) acc = fmaf(pooled[k], hw[d * DM + k], acc);
    out[b * 2 + d] = acc;
  }
}

}  // namespace

extern "C" void kernel_launch(void* const* d_in, const int* in_sizes, int n_in,
                              void* d_out, int out_size, void* d_ws, size_t ws_size,
                              hipStream_t stream) {
  const int*   ids    = (const int*)d_in[0];
  const int*   mask   = (const int*)d_in[1];
  const float* embed  = (const float*)d_in[2];
  const float* cls    = (const float*)d_in[3];
  const float* norm_w = (const float*)d_in[4];
  const float* in_w   = (const float*)d_in[5];
  const float* conv_w = (const float*)d_in[6];
  const float* conv_b = (const float*)d_in[7];
  const float* xp_w   = (const float*)d_in[8];
  const float* dtw    = (const float*)d_in[9];
  const float* dtb    = (const float*)d_in[10];
  const float* Alog   = (const float*)d_in[11];
  const float* Dpar   = (const float*)d_in[12];
  const float* ow     = (const float*)d_in[13];
  const float* fnw    = (const float*)d_in[14];
  const float* hw     = (const float*)d_in[15];
  const float* hb     = (const float*)d_in[16];
  float* out = (float*)d_out;

  char* base = (char*)d_ws;
  size_t off = 0;
  auto alloc = [&](size_t bytes) -> void* {
    void* p = base + off;
    off = (off + bytes + 255) & ~(size_t)255;
    return p;
  };

  float* x      = (float*)alloc((size_t)NB * LSEQ * DM * 4);
  unsigned short* h16 = (unsigned short*)alloc((size_t)NB * LSEQ * DM * 2);
  unsigned short* xz16 = (unsigned short*)alloc((size_t)NB * LSEQ * DXZ * 2);
  unsigned short* xi16 = (unsigned short*)alloc((size_t)NB * LSEQ * DI * 2);
  float* dblb   = (float*)alloc((size_t)NB * LSEQ * DBLW * 4);
  float* dtbuf  = (float*)alloc((size_t)NB * LSEQ * DI * 4);
  unsigned short* yb0 = (unsigned short*)alloc((size_t)NB * LSEQ * DI * 2);
  unsigned short* yb1 = (unsigned short*)alloc((size_t)NB * LSEQ * DI * 2);
  unsigned short* wb_in = (unsigned short*)alloc((size_t)8 * DXZ * DM * 2);
  unsigned short* wb_xp = (unsigned short*)alloc((size_t)8 * XPAD * DI * 2);
  unsigned short* wb_ow = (unsigned short*)alloc((size_t)8 * DM * DI * 2);
  float* wT_dt  = (float*)alloc((size_t)8 * DTR * DI * 4);
  float* partial = (float*)alloc((size_t)NB * 64 * DM * 4);
  float* cumdt  = (float*)alloc((size_t)NB * NDG * NCH1 * 64 * 4);
  unsigned short* Hbuf = (unsigned short*)alloc((size_t)NB * NDG * NCH * NST * 64 * 2);

  cvt_bf16_kernel<<<(8 * DXZ * DM + 255) / 256, 256, 0, stream>>>(in_w, wb_in, 8 * DXZ * DM);
  pad_xp_kernel<<<(8 * XPAD * DI + 255) / 256, 256, 0, stream>>>(xp_w, wb_xp);
  cvt_bf16_kernel<<<(8 * DM * DI + 255) / 256, 256, 0, stream>>>(ow, wb_ow, 8 * DM * DI);
  dim3 tb(32, 8);
  transpose_batched<<<dim3(1, 12, 8), tb, 0, stream>>>(dtw, wT_dt, DI, DTR);

  embed_kernel<<<(NB * LSEQ * DM) / 256, 256, 0, stream>>>(ids, embed, cls, x);

  const int mtiles = (MROWS + 127) / 128;  // 65
  for (int l = 0; l < 8; ++l) {
    rmsnorm_kernel<<<MROWS, 192, 0, stream>>>(x, norm_w + l * DM, h16);
    // xz16 = bf16(h @ in_w^T)
    gemm_mfma<2, 0><<<dim3(DXZ / 64, mtiles), 256, 0, stream>>>(
        h16, nullptr, nullptr, wb_in + (size_t)l * DXZ * DM, nullptr, xz16,
        MROWS, DXZ, DXZ, DM, DXZ);
    conv_kernel<<<(NB * LSEQ * DI) / 256, 256, 0, stream>>>(
        xz16, conv_w + l * DI * 3, conv_b + l * DI, xi16);
    // dblb = xi @ xp_w^T  (fp32)
    gemm_mfma<0, 0><<<dim3(XPAD / 64 + 1, mtiles), 256, 0, stream>>>(
        xi16, nullptr, nullptr, wb_xp + (size_t)l * XPAD * DI, dblb, nullptr,
        MROWS, XPAD, DBLW, DI, DBLW);
    dt_kernel<<<MROWS / 4, DI, 0, stream>>>(dblb, wT_dt + l * DTR * DI, dtb + l * DI, dtbuf);
    // chunked scan (384-thr blocks, gate fused in pass3)
    scan_pass1<<<NB * NCH1 * 2, 384, 0, stream>>>(
        dtbuf, xi16, dblb, Alog + (size_t)l * DI * NST, cumdt, Hbuf);
    scan_pass2<<<(NB * NDG * 16) / 4, 256, 0, stream>>>(
        cumdt, Alog + (size_t)l * DI * NST, Hbuf);
    scan_pass3<<<NB * NCH * 2, 384, 0, stream>>>(
        dtbuf, xi16, xz16, dblb, Alog + (size_t)l * DI * NST, Dpar + l * DI, Hbuf,
        yb0, yb1);
    // x += bf16sum(yb0, yb1) @ ow^T
    gemm_mfma<1, 1><<<dim3(DM / 64, mtiles), 256, 0, stream>>>(
        nullptr, yb0, yb1, wb_ow + (size_t)l * DM * DI, x, nullptr,
        MROWS, DM, DM, DI, DM);
  }

  pool1_kernel<<<NB * 64, 192, 0, stream>>>(x, mask, fnw, partial);
  pool2_kernel<<<NB, 192, 0, stream>>>(partial, mask, hw, hb, out);
}

// Round 17
// 1236.593 us; speedup vs baseline: 1.2276x; 1.2276x over previous
//
#include <hip/hip_runtime.h>
#include <hip/hip_bf16.h>
#include <cstddef>

namespace {

constexpr int NB   = 8;     // batch
constexpr int LSEQ = 1025;  // tokens incl. CLS
constexpr int TSEQ = 1024;
constexpr int DM   = 192;   // d_model
constexpr int DI   = 384;   // d_inner
constexpr int DXZ  = 768;   // 2*d_inner
constexpr int DBLW = 140;   // dt_rank + 2*d_state
constexpr int DTR  = 12;    // dt_rank
constexpr int NST  = 64;    // d_state
constexpr int MROWS = NB * LSEQ;  // 8200
constexpr int NCH  = 32;    // scan chunks
constexpr int CS   = 32;    // chunk size (last chunk = 33)
constexpr int NCH1 = NCH - 1;
constexpr int NDG  = DI / 64;  // 6 channel groups
constexpr int HST  = 32;    // states per wave (half split)
constexpr int XPAD = 144;   // padded rows for xp weight
constexpr float LOG2E = 1.4426950408889634f;

using bf16x8 = __attribute__((ext_vector_type(8))) short;
using f32x4  = __attribute__((ext_vector_type(4))) float;

__device__ __forceinline__ float waveReduceSum(float v) {
#pragma unroll
  for (int o = 32; o; o >>= 1) v += __shfl_xor(v, o, 64);
  return v;
}

__device__ __forceinline__ unsigned short f2bf(float v) {
  __hip_bfloat16 b = __float2bfloat16(v);
  return *reinterpret_cast<unsigned short*>(&b);
}
__device__ __forceinline__ float bf2f(unsigned short u) {
  return __uint_as_float(((unsigned)u) << 16);
}
__device__ __forceinline__ float lo16(unsigned v) { return __uint_as_float(v << 16); }
__device__ __forceinline__ float hi16(unsigned v) { return __uint_as_float(v & 0xffff0000u); }
// add two packed bf16 pairs in fp32, repack
__device__ __forceinline__ unsigned addpair_bf(unsigned a, unsigned b) {
  float alo = lo16(a), ahi = hi16(a);
  float blo = lo16(b), bhi = hi16(b);
  return ((unsigned)f2bf(alo + blo)) | (((unsigned)f2bf(ahi + bhi)) << 16);
}

// ---------------- embed ----------------
__global__ void embed_kernel(const int* __restrict__ ids, const float* __restrict__ emb,
                             const float* __restrict__ cls, float* __restrict__ x) {
  int idx = blockIdx.x * blockDim.x + threadIdx.x;
  if (idx >= NB * LSEQ * DM) return;
  int d = idx % DM;
  int bt = idx / DM;
  int t = bt % LSEQ, b = bt / LSEQ;
  float v;
  if (t < TSEQ) v = emb[(size_t)ids[b * TSEQ + t] * DM + d];
  else          v = cls[d];
  x[idx] = v;
}

// ---------------- weight conversion ----------------
__global__ void cvt_bf16_kernel(const float* __restrict__ src, unsigned short* __restrict__ dst,
                                int n) {
  int idx = blockIdx.x * blockDim.x + threadIdx.x;
  if (idx < n) dst[idx] = f2bf(src[idx]);
}

__global__ void pad_xp_kernel(const float* __restrict__ src, unsigned short* __restrict__ dst) {
  int idx = blockIdx.x * blockDim.x + threadIdx.x;
  if (idx >= 8 * XPAD * DI) return;
  int k = idx % DI;
  int n = (idx / DI) % XPAD;
  int l = idx / (DI * XPAD);
  float v = (n < DBLW) ? src[((size_t)l * DBLW + n) * DI + k] : 0.f;
  dst[idx] = f2bf(v);
}

// ---------------- batched transpose (for dtw only) ----------------
__global__ void transpose_batched(const float* __restrict__ in, float* __restrict__ out,
                                  int rows, int cols) {
  __shared__ float tile[32][33];
  int l = blockIdx.z;
  int r0 = blockIdx.y * 32, c0 = blockIdx.x * 32;
  const float* src = in + (size_t)l * rows * cols;
  float* dst = out + (size_t)l * rows * cols;
  int tx = threadIdx.x, ty = threadIdx.y;
#pragma unroll
  for (int i = 0; i < 32; i += 8) {
    int r = r0 + ty + i, c = c0 + tx;
    if (r < rows && c < cols) tile[ty + i][tx] = src[(size_t)r * cols + c];
  }
  __syncthreads();
#pragma unroll
  for (int i = 0; i < 32; i += 8) {
    int c = c0 + ty + i, r = r0 + tx;
    if (c < cols && r < rows) dst[(size_t)c * rows + r] = tile[tx][ty + i];
  }
}

// ---------------- rmsnorm -> bf16 ----------------
__global__ __launch_bounds__(192)
void rmsnorm_kernel(const float* __restrict__ x, const float* __restrict__ w,
                    unsigned short* __restrict__ h) {
  int row = blockIdx.x;
  int d = threadIdx.x;
  float v = x[(size_t)row * DM + d];
  float ss = waveReduceSum(v * v);
  __shared__ float red[3];
  if ((d & 63) == 0) red[d >> 6] = ss;
  __syncthreads();
  float ms = (red[0] + red[1] + red[2]) * (1.f / DM);
  h[(size_t)row * DM + d] = f2bf(v * rsqrtf(ms + 1e-6f) * w[d]);
}

// ---------------- bf16 MFMA GEMM: C[M,*] op= A[M,K] @ W[N,K]^T ----------------
// EPI: 0 = store fp32 C, 1 = += fp32 C, 2 = store bf16 Cb.
// ASRC: 0 = A bf16, 1 = A = bf16sum(Ab0, Ab1) (both bf16).
template <int EPI, int ASRC>
__global__ __launch_bounds__(256)
void gemm_mfma(const unsigned short* __restrict__ A, const unsigned short* __restrict__ Ab0,
               const unsigned short* __restrict__ Ab1, const unsigned short* __restrict__ W,
               float* __restrict__ C, unsigned short* __restrict__ Cb,
               int M, int Nw, int Nstore, int K, int ldc) {
  __shared__ unsigned short Alds[128][40];
  __shared__ unsigned short Wlds[64][40];
  const int tid = threadIdx.x;
  const int w = tid >> 6, lane = tid & 63;
  const int r16 = lane & 15, g = lane >> 4;
  const int row0 = blockIdx.y * 128, col0 = blockIdx.x * 64;

  f32x4 acc[2][4];
#pragma unroll
  for (int mi = 0; mi < 2; ++mi)
#pragma unroll
    for (int ni = 0; ni < 4; ++ni) acc[mi][ni] = (f32x4){0.f, 0.f, 0.f, 0.f};

  for (int k0 = 0; k0 < K; k0 += 32) {
#pragma unroll
    for (int cc = 0; cc < 2; ++cc) {
      int c = tid + cc * 256;
      int r = c >> 2, q = c & 3;
      uint4 v = make_uint4(0, 0, 0, 0);
      int grow = row0 + r;
      if (grow < M) {
        if (ASRC == 0) {
          v = *(const uint4*)(A + (size_t)grow * K + k0 + q * 8);
        } else {
          uint4 a = *(const uint4*)(Ab0 + (size_t)grow * K + k0 + q * 8);
          uint4 b = *(const uint4*)(Ab1 + (size_t)grow * K + k0 + q * 8);
          v.x = addpair_bf(a.x, b.x);
          v.y = addpair_bf(a.y, b.y);
          v.z = addpair_bf(a.z, b.z);
          v.w = addpair_bf(a.w, b.w);
        }
      }
      *(uint4*)&Alds[r][q * 8] = v;
    }
    {
      int r = tid >> 2, q = tid & 3;
      uint4 v = make_uint4(0, 0, 0, 0);
      int gn = col0 + r;
      if (gn < Nw) v = *(const uint4*)(W + (size_t)gn * K + k0 + q * 8);
      *(uint4*)&Wlds[r][q * 8] = v;
    }
    __syncthreads();
    bf16x8 a_f[2], b_f[4];
#pragma unroll
    for (int mi = 0; mi < 2; ++mi)
      a_f[mi] = *(const bf16x8*)&Alds[w * 32 + mi * 16 + r16][g * 8];
#pragma unroll
    for (int ni = 0; ni < 4; ++ni)
      b_f[ni] = *(const bf16x8*)&Wlds[ni * 16 + r16][g * 8];
#pragma unroll
    for (int mi = 0; mi < 2; ++mi)
#pragma unroll
      for (int ni = 0; ni < 4; ++ni)
        acc[mi][ni] = __builtin_amdgcn_mfma_f32_16x16x32_bf16(a_f[mi], b_f[ni],
                                                              acc[mi][ni], 0, 0, 0);
    __syncthreads();
  }
#pragma unroll
  for (int mi = 0; mi < 2; ++mi) {
#pragma unroll
    for (int reg = 0; reg < 4; ++reg) {
      int row = row0 + w * 32 + mi * 16 + g * 4 + reg;
      if (row >= M) continue;
#pragma unroll
      for (int ni = 0; ni < 4; ++ni) {
        int col = col0 + ni * 16 + r16;
        if (col >= Nstore) continue;
        size_t idx = (size_t)row * ldc + col;
        if (EPI == 1)      C[idx] += acc[mi][ni][reg];
        else if (EPI == 0) C[idx] = acc[mi][ni][reg];
        else               Cb[idx] = f2bf(acc[mi][ni][reg]);
      }
    }
  }
}

// ------- depthwise causal conv3 (bf16 in) + bias + silu -> bf16, zg16 = bf16(silu(z)) -------
__global__ void conv_kernel(const unsigned short* __restrict__ xz16, const float* __restrict__ cw,
                            const float* __restrict__ cb,
                            unsigned short* __restrict__ xi16,
                            unsigned short* __restrict__ zg16) {
  int idx = blockIdx.x * blockDim.x + threadIdx.x;
  if (idx >= NB * LSEQ * DI) return;
  int c = idx % DI;
  int bt = idx / DI;
  int t = bt % LSEQ, b = bt / LSEQ;
  const unsigned short* src = xz16 + (size_t)b * LSEQ * DXZ + c;
  float s = cb[c];
  float w0 = cw[c * 3 + 0], w1 = cw[c * 3 + 1], w2 = cw[c * 3 + 2];
  if (t >= 2) s = fmaf(w0, bf2f(src[(size_t)(t - 2) * DXZ]), s);
  if (t >= 1) s = fmaf(w1, bf2f(src[(size_t)(t - 1) * DXZ]), s);
  s = fmaf(w2, bf2f(src[(size_t)t * DXZ]), s);
  float sig = 1.f / (1.f + __expf(-s));
  float u = s * sig;
  xi16[idx] = f2bf(u);
  float zv = bf2f(src[(size_t)t * DXZ + DI]);
  float zsig = 1.f / (1.f + __expf(-zv));
  zg16[idx] = f2bf(zv * zsig);
}

// ---------------- dt = softplus(dt_r @ dtwT + dtb), 4 rows per block ----------------
__global__ __launch_bounds__(384)
void dt_kernel(const float* __restrict__ dbl, const float* __restrict__ dtwT,
               const float* __restrict__ dtb, float* __restrict__ dtout) {
  int row0 = blockIdx.x * 4;
  int d = threadIdx.x;
  __shared__ float rr[4][DTR];
  if (d < 4 * DTR) rr[d / DTR][d % DTR] = dbl[(size_t)(row0 + d / DTR) * DBLW + (d % DTR)];
  float w[DTR];
#pragma unroll
  for (int r = 0; r < DTR; ++r) w[r] = dtwT[r * DI + d];
  float bias = dtb[d];
  __syncthreads();
#pragma unroll
  for (int q = 0; q < 4; ++q) {
    float s = bias;
#pragma unroll
    for (int r = 0; r < DTR; ++r) s = fmaf(rr[q][r], w[r], s);
    float sp = fmaxf(s, 0.f) + log1pf(__expf(-fabsf(s)));
    dtout[(size_t)(row0 + q) * DI + d] = sp;
  }
}

// ======== chunked selective scan, CS=32/NCH=32 ========
// block = (b, chunk), 768 threads = 12 waves = 6 dgroups x 2 state-halves.
// B/C tiles staged ONCE per block (fp32 LDS), shared by all 6 dgroups.
// FAST PATH (A_log structure a_n = -(n+1), __all-guarded): dA[n] = r^(n+1).
// H layout: H[((bg*NCH + c)*NST + n)*64 + lane]; pass1 -> H[c+1], pass2 in place.

__global__ __launch_bounds__(768, 3)
void scan_pass1(const float* __restrict__ dtp_, const unsigned short* __restrict__ xi16,
                const float* __restrict__ dbl, const float* __restrict__ Alog,
                float* __restrict__ cumdt, float* __restrict__ H) {
  __shared__ float Bt[CS][64];
  const int tid = threadIdx.x;
  const int w = tid >> 6, lane = tid & 63;
  const int dgrp = w >> 1, half = w & 1;
  const int b = blockIdx.x / NCH1;
  const int c = blockIdx.x % NCH1;
  const int bg = b * NDG + dgrp;
  const int d = dgrp * 64 + lane;
  const int n0 = half * HST;
  const int t0 = c * CS;

  {  // stage B tile once, all 12 waves
    const float* srcB = dbl + ((size_t)b * LSEQ + t0) * DBLW + DTR + lane;
    for (int r = w; r < CS; r += 12) Bt[r][lane] = srcB[(size_t)r * DBLW];
  }

  const float* Ap = Alog + (size_t)d * NST;
  float a0 = __expf(Ap[0]);
  bool okl = true;
#pragma unroll
  for (int j = 0; j < HST; ++j) {
    float aj = __expf(Ap[n0 + j]);
    okl = okl && (fabsf(aj - (float)(n0 + j + 1) * a0) <= 1e-3f * (float)(n0 + j + 1) * fabsf(a0));
  }
  const bool fast = __all(okl);
  const float al2u = -a0 * LOG2E;

  float h[HST];
#pragma unroll
  for (int j = 0; j < HST; ++j) h[j] = 0.f;

  __syncthreads();

  const float* dtp = dtp_ + ((size_t)b * LSEQ + t0) * DI + d;
  const unsigned short* up = xi16 + ((size_t)b * LSEQ + t0) * DI + d;
  float cum = 0.f;
  float dtv = *dtp, uv = bf2f(*up);

  if (fast) {
    for (int t = 0; t < CS; ++t) {
      float n_dt = 0.f, n_u = 0.f;
      if (t + 1 < CS) {
        dtp += DI; up += DI;
        n_dt = *dtp; n_u = bf2f(*up);
      }
      float dtu = dtv * uv;
      float m = dtv * al2u;
      float r1 = exp2f(m);
      float p = (n0 == 0) ? r1 : exp2f(m * (float)(n0 + 1));
      float r2 = r1 * r1, r4 = r2 * r2;
      float s0 = p, s1 = p * r1, s2 = p * r2, s3 = s2 * r1;
#pragma unroll
      for (int k = 0; k < 8; ++k) {
        float4 B4 = *(const float4*)&Bt[t][n0 + 4 * k];
        h[4 * k + 0] = fmaf(s0, h[4 * k + 0], dtu * B4.x);
        h[4 * k + 1] = fmaf(s1, h[4 * k + 1], dtu * B4.y);
        h[4 * k + 2] = fmaf(s2, h[4 * k + 2], dtu * B4.z);
        h[4 * k + 3] = fmaf(s3, h[4 * k + 3], dtu * B4.w);
        if (k < 7) { s0 *= r4; s1 *= r4; s2 *= r4; s3 *= r4; }
      }
      cum += dtv;
      dtv = n_dt; uv = n_u;
    }
  } else {
    for (int t = 0; t < CS; ++t) {
      float n_dt = 0.f, n_u = 0.f;
      if (t + 1 < CS) {
        dtp += DI; up += DI;
        n_dt = *dtp; n_u = bf2f(*up);
      }
      float dtu = dtv * uv;
      for (int j = 0; j < HST; ++j) {
        float aj = -__expf(Ap[n0 + j]) * LOG2E;
        h[j] = fmaf(exp2f(dtv * aj), h[j], dtu * Bt[t][n0 + j]);
      }
      cum += dtv;
      dtv = n_dt; uv = n_u;
    }
  }

  if (half == 0)
    cumdt[(size_t)bg * NCH1 * 64 + (size_t)c * 64 + lane] = cum;
  float* hp = H + ((size_t)bg * NCH + (c + 1)) * NST * 64 + (size_t)n0 * 64 + lane;
#pragma unroll
  for (int j = 0; j < HST; ++j) hp[j * 64] = h[j];
}

// pass2: in-place combine. wave = (bg, 4 states); grid = NB*NDG*16/4 blocks of 4 waves
__global__ __launch_bounds__(256)
void scan_pass2(const float* __restrict__ cumdt, const float* __restrict__ Alog,
                float* __restrict__ H) {
  int gw = blockIdx.x * 4 + (threadIdx.x >> 6);   // wave id over NB*NDG*16
  int lane = threadIdx.x & 63;
  int bg = gw >> 4;
  int nq = (gw & 15) * 4;
  int dgrp = bg % NDG;
  int d = dgrp * 64 + lane;

  float al2[4];
#pragma unroll
  for (int j = 0; j < 4; ++j) al2[j] = -__expf(Alog[(size_t)d * NST + nq + j]) * LOG2E;

  float h[4] = {0.f, 0.f, 0.f, 0.f};

  float* H0 = H + ((size_t)bg * NCH) * NST * 64 + (size_t)nq * 64 + lane;
#pragma unroll
  for (int j = 0; j < 4; ++j) H0[j * 64] = 0.f;

  for (int c = 1; c < NCH; ++c) {
    float cum = cumdt[(size_t)bg * NCH1 * 64 + (size_t)(c - 1) * 64 + lane];
    float* Hc = H + ((size_t)bg * NCH + c) * NST * 64 + (size_t)nq * 64 + lane;
#pragma unroll
    for (int j = 0; j < 4; ++j) {
      float he = Hc[j * 64];
      h[j] = fmaf(exp2f(al2[j] * cum), h[j], he);
      Hc[j * 64] = h[j];
    }
  }
}

// pass3: scan from H[c]; half0 -> yb0 (incl. D-skip), half1 -> yb1; both gated, bf16 out
__global__ __launch_bounds__(768, 3)
void scan_pass3(const float* __restrict__ dtp_, const unsigned short* __restrict__ xi16,
                const unsigned short* __restrict__ zg16, const float* __restrict__ dbl,
                const float* __restrict__ Alog, const float* __restrict__ Dpar,
                const float* __restrict__ H, unsigned short* __restrict__ yb0,
                unsigned short* __restrict__ yb1) {
  __shared__ float Bt[CS + 1][64];
  __shared__ float Ct[CS + 1][64];
  const int tid = threadIdx.x;
  const int w = tid >> 6, lane = tid & 63;
  const int dgrp = w >> 1, half = w & 1;
  const int b = blockIdx.x >> 5;
  const int c = blockIdx.x & 31;
  const int bg = b * NDG + dgrp;
  const int d = dgrp * 64 + lane;
  const int n0 = half * HST;
  const int t0 = c * CS;
  const int nsteps = (c == NCH - 1) ? (LSEQ - t0) : CS;   // 32 or 33

  {  // stage B (waves 0-5) and C (waves 6-11) once per block
    if (w < 6) {
      const float* srcB = dbl + ((size_t)b * LSEQ + t0) * DBLW + DTR + lane;
      for (int r = w; r < nsteps; r += 6) Bt[r][lane] = srcB[(size_t)r * DBLW];
    } else {
      const float* srcC = dbl + ((size_t)b * LSEQ + t0) * DBLW + DTR + NST + lane;
      for (int r = w - 6; r < nsteps; r += 6) Ct[r][lane] = srcC[(size_t)r * DBLW];
    }
  }

  const float* Ap = Alog + (size_t)d * NST;
  float a0 = __expf(Ap[0]);
  bool okl = true;
#pragma unroll
  for (int j = 0; j < HST; ++j) {
    float aj = __expf(Ap[n0 + j]);
    okl = okl && (fabsf(aj - (float)(n0 + j + 1) * a0) <= 1e-3f * (float)(n0 + j + 1) * fabsf(a0));
  }
  const bool fast = __all(okl);
  const float al2u = -a0 * LOG2E;

  float Dp = Dpar[d];
  float h[HST];
  {
    const float* hi = H + ((size_t)bg * NCH + c) * NST * 64 + (size_t)n0 * 64 + lane;
#pragma unroll
    for (int j = 0; j < HST; ++j) h[j] = hi[j * 64];
  }

  __syncthreads();

  const float* dtp = dtp_ + ((size_t)b * LSEQ + t0) * DI + d;
  const unsigned short* up = xi16 + ((size_t)b * LSEQ + t0) * DI + d;
  const unsigned short* gp = zg16 + ((size_t)b * LSEQ + t0) * DI + d;
  unsigned short* yp = (half == 0 ? yb0 : yb1) + ((size_t)b * LSEQ + t0) * DI + d;

  float dtv = *dtp, uv = bf2f(*up), gv = bf2f(*gp);

  if (fast) {
    for (int t = 0; t < nsteps; ++t) {
      float n_dt = 0.f, n_u = 0.f, n_g = 0.f;
      if (t + 1 < nsteps) {
        dtp += DI; up += DI; gp += DI;
        n_dt = *dtp; n_u = bf2f(*up); n_g = bf2f(*gp);
      }
      float dtu = dtv * uv;
      float m = dtv * al2u;
      float r1 = exp2f(m);
      float p = (n0 == 0) ? r1 : exp2f(m * (float)(n0 + 1));
      float r2 = r1 * r1, r4 = r2 * r2;
      float s0 = p, s1 = p * r1, s2 = p * r2, s3 = s2 * r1;
      float y = 0.f;
#pragma unroll
      for (int k = 0; k < 8; ++k) {
        float4 B4 = *(const float4*)&Bt[t][n0 + 4 * k];
        float4 C4 = *(const float4*)&Ct[t][n0 + 4 * k];
        h[4 * k + 0] = fmaf(s0, h[4 * k + 0], dtu * B4.x);
        y = fmaf(h[4 * k + 0], C4.x, y);
        h[4 * k + 1] = fmaf(s1, h[4 * k + 1], dtu * B4.y);
        y = fmaf(h[4 * k + 1], C4.y, y);
        h[4 * k + 2] = fmaf(s2, h[4 * k + 2], dtu * B4.z);
        y = fmaf(h[4 * k + 2], C4.z, y);
        h[4 * k + 3] = fmaf(s3, h[4 * k + 3], dtu * B4.w);
        y = fmaf(h[4 * k + 3], C4.w, y);
        if (k < 7) { s0 *= r4; s1 *= r4; s2 *= r4; s3 *= r4; }
      }
      float outv = (half == 0) ? fmaf(uv, Dp, y) * gv : y * gv;
      *yp = f2bf(outv);
      yp += DI;
      dtv = n_dt; uv = n_u; gv = n_g;
    }
  } else {
    for (int t = 0; t < nsteps; ++t) {
      float n_dt = 0.f, n_u = 0.f, n_g = 0.f;
      if (t + 1 < nsteps) {
        dtp += DI; up += DI; gp += DI;
        n_dt = *dtp; n_u = bf2f(*up); n_g = bf2f(*gp);
      }
      float dtu = dtv * uv;
      float y = 0.f;
      for (int j = 0; j < HST; ++j) {
        float aj = -__expf(Ap[n0 + j]) * LOG2E;
        h[j] = fmaf(exp2f(dtv * aj), h[j], dtu * Bt[t][n0 + j]);
        y = fmaf(h[j], Ct[t][n0 + j], y);
      }
      float outv = (half == 0) ? fmaf(uv, Dp, y) * gv : y * gv;
      *yp = f2bf(outv);
      yp += DI;
      dtv = n_dt; uv = n_u; gv = n_g;
    }
  }
}

// ---------------- final norm + masked mean pool + head ------------
__global__ __launch_bounds__(192)
void pool1_kernel(const float* __restrict__ x, const int* __restrict__ mask,
                  const float* __restrict__ fw, float* __restrict__ partial) {
  int b = blockIdx.x >> 6;
  int chunk = blockIdx.x & 63;
  int d = threadIdx.x;
  __shared__ float red[3];
  float w = fw[d];
  float acc = 0.f;
  for (int tt = 0; tt < 16; ++tt) {
    int t = chunk * 16 + tt;
    float v = x[((size_t)b * LSEQ + t) * DM + d];
    float ss = waveReduceSum(v * v);
    if ((d & 63) == 0) red[d >> 6] = ss;
    __syncthreads();
    float ms = (red[0] + red[1] + red[2]) * (1.f / DM);
    float m = (float)mask[b * TSEQ + t];
    acc = fmaf(v * rsqrtf(ms + 1e-6f) * w, m, acc);
    __syncthreads();
  }
  partial[((size_t)b * 64 + chunk) * DM + d] = acc;
}

__global__ __launch_bounds__(192)
void pool2_kernel(const float* __restrict__ partial, const int* __restrict__ mask,
                  const float* __restrict__ hw, const float* __restrict__ hb,
                  float* __restrict__ out) {
  int b = blockIdx.x;
  int d = threadIdx.x;
  float s = 0.f;
  for (int c = 0; c < 64; ++c) s += partial[((size_t)b * 64 + c) * DM + d];
  float den = 0.f;
  for (int t = d; t < TSEQ; t += DM) den += (float)mask[b * TSEQ + t];
  den = waveReduceSum(den);
  __shared__ float dred[3];
  __shared__ float pooled[DM];
  if ((d & 63) == 0) dred[d >> 6] = den;
  __syncthreads();
  float denom = fmaxf(dred[0] + dred[1] + dred[2], 1.f);
  pooled[d] = s / denom;
  __syncthreads();
  if (d < 2) {
    float acc = hb[d];
    for (int k = 0; k < DM; ++k) acc = fmaf(pooled[k], hw[d * DM + k], acc);
    out[b * 2 + d] = acc;
  }
}

}  // namespace

extern "C" void kernel_launch(void* const* d_in, const int* in_sizes, int n_in,
                              void* d_out, int out_size, void* d_ws, size_t ws_size,
                              hipStream_t stream) {
  const int*   ids    = (const int*)d_in[0];
  const int*   mask   = (const int*)d_in[1];
  const float* embed  = (const float*)d_in[2];
  const float* cls    = (const float*)d_in[3];
  const float* norm_w = (const float*)d_in[4];
  const float* in_w   = (const float*)d_in[5];
  const float* conv_w = (const float*)d_in[6];
  const float* conv_b = (const float*)d_in[7];
  const float* xp_w   = (const float*)d_in[8];
  const float* dtw    = (const float*)d_in[9];
  const float* dtb    = (const float*)d_in[10];
  const float* Alog   = (const float*)d_in[11];
  const float* Dpar   = (const float*)d_in[12];
  const float* ow     = (const float*)d_in[13];
  const float* fnw    = (const float*)d_in[14];
  const float* hw     = (const float*)d_in[15];
  const float* hb     = (const float*)d_in[16];
  float* out = (float*)d_out;

  char* base = (char*)d_ws;
  size_t off = 0;
  auto alloc = [&](size_t bytes) -> void* {
    void* p = base + off;
    off = (off + bytes + 255) & ~(size_t)255;
    return p;
  };

  float* x      = (float*)alloc((size_t)NB * LSEQ * DM * 4);
  unsigned short* h16 = (unsigned short*)alloc((size_t)NB * LSEQ * DM * 2);
  unsigned short* xz16 = (unsigned short*)alloc((size_t)NB * LSEQ * DXZ * 2);
  unsigned short* xi16 = (unsigned short*)alloc((size_t)NB * LSEQ * DI * 2);
  unsigned short* zg16 = (unsigned short*)alloc((size_t)NB * LSEQ * DI * 2);
  float* dblb   = (float*)alloc((size_t)NB * LSEQ * DBLW * 4);
  float* dtbuf  = (float*)alloc((size_t)NB * LSEQ * DI * 4);
  unsigned short* yb0 = (unsigned short*)alloc((size_t)NB * LSEQ * DI * 2);
  unsigned short* yb1 = (unsigned short*)alloc((size_t)NB * LSEQ * DI * 2);
  unsigned short* wb_in = (unsigned short*)alloc((size_t)8 * DXZ * DM * 2);
  unsigned short* wb_xp = (unsigned short*)alloc((size_t)8 * XPAD * DI * 2);
  unsigned short* wb_ow = (unsigned short*)alloc((size_t)8 * DM * DI * 2);
  float* wT_dt  = (float*)alloc((size_t)8 * DTR * DI * 4);
  float* partial = (float*)alloc((size_t)NB * 64 * DM * 4);
  float* cumdt  = (float*)alloc((size_t)NB * NDG * NCH1 * 64 * 4);
  float* Hbuf   = (float*)alloc((size_t)NB * NDG * NCH * NST * 64 * 4);  // 25.2MB

  cvt_bf16_kernel<<<(8 * DXZ * DM + 255) / 256, 256, 0, stream>>>(in_w, wb_in, 8 * DXZ * DM);
  pad_xp_kernel<<<(8 * XPAD * DI + 255) / 256, 256, 0, stream>>>(xp_w, wb_xp);
  cvt_bf16_kernel<<<(8 * DM * DI + 255) / 256, 256, 0, stream>>>(ow, wb_ow, 8 * DM * DI);
  dim3 tb(32, 8);
  transpose_batched<<<dim3(1, 12, 8), tb, 0, stream>>>(dtw, wT_dt, DI, DTR);

  embed_kernel<<<(NB * LSEQ * DM) / 256, 256, 0, stream>>>(ids, embed, cls, x);

  const int mtiles = (MROWS + 127) / 128;  // 65
  for (int l = 0; l < 8; ++l) {
    rmsnorm_kernel<<<MROWS, 192, 0, stream>>>(x, norm_w + l * DM, h16);
    // xz16 = bf16(h @ in_w^T)
    gemm_mfma<2, 0><<<dim3(DXZ / 64, mtiles), 256, 0, stream>>>(
        h16, nullptr, nullptr, wb_in + (size_t)l * DXZ * DM, nullptr, xz16,
        MROWS, DXZ, DXZ, DM, DXZ);
    conv_kernel<<<(NB * LSEQ * DI) / 256, 256, 0, stream>>>(
        xz16, conv_w + l * DI * 3, conv_b + l * DI, xi16, zg16);
    gemm_mfma<0, 0><<<dim3(XPAD / 64 + 1, mtiles), 256, 0, stream>>>(
        xi16, nullptr, nullptr, wb_xp + (size_t)l * XPAD * DI, dblb, nullptr,
        MROWS, XPAD, DBLW, DI, DBLW);
    dt_kernel<<<MROWS / 4, DI, 0, stream>>>(dblb, wT_dt + l * DTR * DI, dtb + l * DI, dtbuf);
    // chunked scan
    scan_pass1<<<NB * NCH1, 768, 0, stream>>>(
        dtbuf, xi16, dblb, Alog + (size_t)l * DI * NST, cumdt, Hbuf);
    scan_pass2<<<(NB * NDG * 16) / 4, 256, 0, stream>>>(
        cumdt, Alog + (size_t)l * DI * NST, Hbuf);
    scan_pass3<<<NB * NCH, 768, 0, stream>>>(
        dtbuf, xi16, zg16, dblb, Alog + (size_t)l * DI * NST, Dpar + l * DI, Hbuf,
        yb0, yb1);
    // x += bf16sum(yb0, yb1) @ ow^T
    gemm_mfma<1, 1><<<dim3(DM / 64, mtiles), 256, 0, stream>>>(
        nullptr, yb0, yb1, wb_ow + (size_t)l * DM * DI, x, nullptr,
        MROWS, DM, DM, DI, DM);
  }

  pool1_kernel<<<NB * 64, 192, 0, stream>>>(x, mask, fnw, partial);
  pool2_kernel<<<NB, 192, 0, stream>>>(partial, mask, hw, hb, out);
}